// Round 5
// baseline (5434.621 us; speedup 1.0000x reference)
//
#include <hip/hip_runtime.h>
#include <hip/hip_bf16.h>
#include <math.h>

typedef __hip_bfloat16 bf16;

#define S_   1024
#define H_   1024
#define NH_  16
#define D_   64
#define L_   9

// ---------------------------------------------------------------------------
// GEMM: out[M,1024] = A[M,1024] @ W[1024,1024] + bias (+ residual if RES)
// Plain row-major output. block 256, 64x64 tile, 4x4 micro-tile, BK=16.
// ---------------------------------------------------------------------------
template <int RES>
__global__ __launch_bounds__(256) void gemm_rm(
    const float* __restrict__ A, const float* __restrict__ W,
    const float* __restrict__ bias, const float* __restrict__ resid,
    float* __restrict__ out) {
  __shared__ __align__(16) float As[16][68];   // [k][m]
  __shared__ __align__(16) float Bs[16][68];   // [k][n]
  const int bx = blockIdx.x;            // n tile: 0..15
  const int by = blockIdx.y;            // m tile
  const int tid = threadIdx.x;
  const int tx = tid & 15, ty = tid >> 4;
  const int m0 = by * 64, n0 = bx * 64;

  const int arow = tid >> 2, akk = (tid & 3) * 4;   // A: 64(m) x 16(k)
  const int bkk = tid >> 4, bcol = (tid & 15) * 4;  // B: 16(k) x 64(n)

  float acc[4][4];
#pragma unroll
  for (int i = 0; i < 4; i++)
#pragma unroll
    for (int j = 0; j < 4; j++) acc[i][j] = 0.f;

  for (int k0 = 0; k0 < 1024; k0 += 16) {
    float4 av4 = *(const float4*)&A[(size_t)(m0 + arow) * 1024 + k0 + akk];
    float4 bv4 = *(const float4*)&W[(size_t)(k0 + bkk) * 1024 + n0 + bcol];
    As[akk + 0][arow] = av4.x;
    As[akk + 1][arow] = av4.y;
    As[akk + 2][arow] = av4.z;
    As[akk + 3][arow] = av4.w;
    *(float4*)&Bs[bkk][bcol] = bv4;
    __syncthreads();
#pragma unroll
    for (int kk = 0; kk < 16; kk++) {
      float4 av = *(const float4*)&As[kk][ty * 4];
      float4 bv = *(const float4*)&Bs[kk][tx * 4];
      float a[4] = {av.x, av.y, av.z, av.w};
      float b[4] = {bv.x, bv.y, bv.z, bv.w};
#pragma unroll
      for (int i = 0; i < 4; i++)
#pragma unroll
        for (int j = 0; j < 4; j++) acc[i][j] += a[i] * b[j];
    }
    __syncthreads();
  }

#pragma unroll
  for (int i = 0; i < 4; i++) {
    int m = m0 + ty * 4 + i;
    int nbase = n0 + tx * 4;
    float4 o;
    o.x = acc[i][0] + bias[nbase + 0];
    o.y = acc[i][1] + bias[nbase + 1];
    o.z = acc[i][2] + bias[nbase + 2];
    o.w = acc[i][3] + bias[nbase + 3];
    if (RES) {
      float4 r4 = *(const float4*)&resid[(size_t)m * 1024 + nbase];
      o.x += r4.x; o.y += r4.y; o.z += r4.z; o.w += r4.w;
    }
    *(float4*)&out[(size_t)m * 1024 + nbase] = o;
  }
}

// ---------------------------------------------------------------------------
// Attention, one wave per q-row. q,k,v,ctx all row-major [M,1024].
// Head h of token (b,s) -> row b*S+s, cols h*64..h*64+63. Lane = d.
// ---------------------------------------------------------------------------
__global__ __launch_bounds__(256) void attn_rows(
    const float* __restrict__ q, const float* __restrict__ k,
    const float* __restrict__ v, float* __restrict__ ctx) {
  __shared__ float p[4][1024];
  const int tid = threadIdx.x, lane = tid & 63, wave = tid >> 6;
  const int bh = blockIdx.y;                 // chunk-local b*16+h
  const int b = bh >> 4, h = bh & 15;
  const int qi = blockIdx.x * 4 + wave;      // seq position of this wave's row
  const int col = h * 64 + lane;
  const size_t rowQ = (size_t)(b * S_ + qi) * H_;
  const float qv = q[rowQ + col];
  float* pw = p[wave];

  // ---- scores ----
  const size_t kvbase = (size_t)b * S_ * H_ + col;
  for (int j = 0; j < S_; j++) {
    float t = qv * k[kvbase + (size_t)j * H_];
#pragma unroll
    for (int off = 32; off; off >>= 1) t += __shfl_xor(t, off);
    if (lane == 0) {
      float dist = fabsf((float)(qi - j));
      float pb = __expf(-0.1f * fminf(dist, 5.0f));
      pw[j] = (t + pb) * 0.125f - 0.1f * dist;
    }
  }
  __syncthreads();

  // ---- softmax (in-wave over pw) ----
  float mx = -1e30f;
#pragma unroll
  for (int i = 0; i < 16; i++) mx = fmaxf(mx, pw[lane + 64 * i]);
#pragma unroll
  for (int off = 32; off; off >>= 1) mx = fmaxf(mx, __shfl_xor(mx, off));
  float sm = 0.f;
#pragma unroll
  for (int i = 0; i < 16; i++) {
    float e = __expf(pw[lane + 64 * i] - mx);
    pw[lane + 64 * i] = e;
    sm += e;
  }
#pragma unroll
  for (int off = 32; off; off >>= 1) sm += __shfl_xor(sm, off);
  const float rinv = 1.0f / sm;
  __syncthreads();

  // ---- PV ----
  float acc = 0.f;
  for (int j = 0; j < S_; j++) {
    acc += pw[j] * v[kvbase + (size_t)j * H_];
  }
  ctx[rowQ + col] = acc * rinv;
}

// ---------------------------------------------------------------------------
// LayerNorm over H=1024, one block per row, in-place safe
// ---------------------------------------------------------------------------
__global__ __launch_bounds__(256) void ln_kernel(
    const float* __restrict__ y, const float* __restrict__ g,
    const float* __restrict__ bta, float* __restrict__ yn) {
  const int row = blockIdx.x;
  const int tid = threadIdx.x, lane = tid & 63, wave = tid >> 6;
  const float* yr = y + (size_t)row * 1024;
  float vals[4], s = 0.f, s2 = 0.f;
#pragma unroll
  for (int i = 0; i < 4; i++) {
    float t = yr[tid + i * 256];
    vals[i] = t; s += t; s2 += t * t;
  }
#pragma unroll
  for (int off = 32; off; off >>= 1) {
    s += __shfl_xor(s, off);
    s2 += __shfl_xor(s2, off);
  }
  __shared__ float red[8];
  if (lane == 0) { red[wave] = s; red[4 + wave] = s2; }
  __syncthreads();
  s = red[0] + red[1] + red[2] + red[3];
  s2 = red[4] + red[5] + red[6] + red[7];
  float mu = s * (1.0f / 1024.0f);
  float var = s2 * (1.0f / 1024.0f) - mu * mu;
  float inv = rsqrtf(var + 1e-5f);
  float* ynr = yn + (size_t)row * 1024;
#pragma unroll
  for (int i = 0; i < 4; i++) {
    int hh = tid + i * 256;
    ynr[hh] = (vals[i] - mu) * inv * g[hh] + bta[hh];
  }
}

// ---------------------------------------------------------------------------
// Span logits: yn[M,1024] @ Ws[1024,9] + bs. One wave per row.
// ---------------------------------------------------------------------------
__global__ __launch_bounds__(256) void span_kernel(
    const float* __restrict__ yn, const float* __restrict__ Ws,
    const float* __restrict__ bs, float* __restrict__ logits) {
  const int tid = threadIdx.x, lane = tid & 63, wave = tid >> 6;
  const int row = blockIdx.x * 4 + wave;
  float local[9];
#pragma unroll
  for (int l = 0; l < 9; l++) local[l] = 0.f;
  const float* yr = yn + (size_t)row * 1024;
  for (int i = 0; i < 16; i++) {
    int hh = lane + i * 64;
    float yv = yr[hh];
#pragma unroll
    for (int l = 0; l < 9; l++) local[l] += yv * Ws[hh * 9 + l];
  }
#pragma unroll
  for (int l = 0; l < 9; l++) {
    float sv = local[l];
#pragma unroll
    for (int off = 32; off; off >>= 1) sv += __shfl_xor(sv, off);
    if (lane == 0) logits[(size_t)row * 9 + l] = sv + bs[l];
  }
}

// ---------------------------------------------------------------------------
// Entity-bias adjustment + FP32 output. One thread per token.
// ---------------------------------------------------------------------------
__global__ __launch_bounds__(256) void final_kernel(
    const float* __restrict__ logits, const float* __restrict__ eb,
    float* __restrict__ out) {
  const int m = blockIdx.x * 256 + threadIdx.x;  // chunk-local token
  const int i = m & 1023;                        // position within sequence
  float cur[9];
#pragma unroll
  for (int l = 0; l < 9; l++) cur[l] = logits[(size_t)m * 9 + l];
  if (i > 0) {
    const float* prev = logits + (size_t)(m - 1) * 9;
    int am = 0;
    float best = prev[0];
#pragma unroll
    for (int l = 1; l < 9; l++) {
      float pv = prev[l];
      if (pv > best) { best = pv; am = l; }  // strict > == first-max (jnp.argmax)
    }
    if (am == 1) cur[2] += 2.0f * eb[2];     // B_PERSON -> I_PERSON bias
  }
#pragma unroll
  for (int l = 0; l < 9; l++) out[(size_t)m * 9 + l] = cur[l];
}

// ---------------------------------------------------------------------------
// Diagnostic: zero the output and put a decodable code in out[0].
// ---------------------------------------------------------------------------
__global__ __launch_bounds__(256) void diag_kernel(float* __restrict__ out,
                                                   int n, float code) {
  for (int i = blockIdx.x * 256 + threadIdx.x; i < n; i += gridDim.x * 256)
    out[i] = 0.f;
  if (blockIdx.x == 0 && threadIdx.x == 0) out[0] = code;
}

// ---------------------------------------------------------------------------
extern "C" void kernel_launch(void* const* d_in, const int* in_sizes, int n_in,
                              void* d_out, int out_size, void* d_ws, size_t ws_size,
                              hipStream_t stream) {
  // ---- host-side contract probe (constant across calls -> graph-safe) ----
  static const int EXP[15] = {4194304, 1048576, 1024, 1048576, 1024,
                              1048576, 1024, 1048576, 1024, 1024,
                              1024, 9216, 9, 9, 704};
  int first_bad = -1, badcount = 0;
  if (n_in != 15) { first_bad = 15; badcount = 15; }
  else {
    for (int i = 0; i < 15; i++)
      if (in_sizes[i] != EXP[i]) { badcount++; if (first_bad < 0) first_bad = i; }
    if (out_size != 36864) { badcount++; if (first_bad < 0) first_bad = 16; }
  }
  if (badcount > 0) {
    float code = 4096.0f + 256.0f * (float)first_bad +
                 16.0f * (float)(badcount > 15 ? 15 : badcount);
    diag_kernel<<<64, 256, 0, stream>>>((float*)d_out, out_size, code);
    return;
  }

  const float* x    = (const float*)d_in[0];
  const float* Wq   = (const float*)d_in[1];
  const float* bq   = (const float*)d_in[2];
  const float* Wk   = (const float*)d_in[3];
  const float* bk   = (const float*)d_in[4];
  const float* Wv   = (const float*)d_in[5];
  const float* bv   = (const float*)d_in[6];
  const float* Wo   = (const float*)d_in[7];
  const float* bo   = (const float*)d_in[8];
  const float* ln_g = (const float*)d_in[9];
  const float* ln_b = (const float*)d_in[10];
  const float* Ws   = (const float*)d_in[11];
  const float* bs   = (const float*)d_in[12];
  const float* eb   = (const float*)d_in[13];
  float* out = (float*)d_out;       // reference output dtype is float32
  float* ws = (float*)d_ws;

  const size_t PER_B = (size_t)S_ * H_;  // 1 Mi floats per buffer per batch
  int BC = 1;
  if (ws_size >= 4ull * 4 * PER_B * sizeof(float)) BC = 4;
  else if (ws_size >= 2ull * 4 * PER_B * sizeof(float)) BC = 2;

  for (int b0 = 0; b0 < 4; b0 += BC) {
    const size_t SZ = (size_t)BC * PER_B;
    float* q_ws   = ws;
    float* k_ws   = ws + SZ;
    float* v_ws   = ws + 2 * SZ;
    float* ctx_ws = ws + 3 * SZ;
    float* y_ws   = q_ws;    // q dead after attention
    float* lg_ws  = k_ws;    // k dead after attention

    const float* xb = x + (size_t)b0 * S_ * H_;
    const int M = BC * S_;

    dim3 gblk(16, M / 64);
    gemm_rm<0><<<gblk, 256, 0, stream>>>(xb, Wq, bq, nullptr, q_ws);
    gemm_rm<0><<<gblk, 256, 0, stream>>>(xb, Wk, bk, nullptr, k_ws);
    gemm_rm<0><<<gblk, 256, 0, stream>>>(xb, Wv, bv, nullptr, v_ws);
    attn_rows<<<dim3(S_ / 4, BC * NH_), 256, 0, stream>>>(q_ws, k_ws, v_ws, ctx_ws);
    gemm_rm<1><<<gblk, 256, 0, stream>>>(ctx_ws, Wo, bo, xb, y_ws);
    ln_kernel<<<M, 256, 0, stream>>>(y_ws, ln_g, ln_b, y_ws);
    span_kernel<<<M / 4, 256, 0, stream>>>(y_ws, Ws, bs, lg_ws);
    final_kernel<<<M / 256, 256, 0, stream>>>(lg_ws, eb, out + (size_t)b0 * S_ * L_);
  }
}

// Round 7
// 993.524 us; speedup vs baseline: 5.4700x; 5.4700x over previous
//
#include <hip/hip_runtime.h>
#include <hip/hip_bf16.h>
#include <math.h>

typedef __hip_bfloat16 bf16;

#define S_   1024
#define H_   1024
#define NH_  16
#define D_   64
#define L_   9

// ---------------------------------------------------------------------------
// GEMM: out[M,1024] = A[M,1024] @ W[1024,1024] + bias (+ residual if RES)
// Plain row-major output. block 256, 64x64 tile, 4x4 micro-tile, BK=16.
// Verified correct + near fp32 vector peak (R5).
// ---------------------------------------------------------------------------
template <int RES>
__global__ __launch_bounds__(256) void gemm_rm(
    const float* __restrict__ A, const float* __restrict__ W,
    const float* __restrict__ bias, const float* __restrict__ resid,
    float* __restrict__ out) {
  __shared__ __align__(16) float As[16][68];   // [k][m]
  __shared__ __align__(16) float Bs[16][68];   // [k][n]
  const int bx = blockIdx.x;            // n tile: 0..15
  const int by = blockIdx.y;            // m tile
  const int tid = threadIdx.x;
  const int tx = tid & 15, ty = tid >> 4;
  const int m0 = by * 64, n0 = bx * 64;

  const int arow = tid >> 2, akk = (tid & 3) * 4;   // A: 64(m) x 16(k)
  const int bkk = tid >> 4, bcol = (tid & 15) * 4;  // B: 16(k) x 64(n)

  float acc[4][4];
#pragma unroll
  for (int i = 0; i < 4; i++)
#pragma unroll
    for (int j = 0; j < 4; j++) acc[i][j] = 0.f;

  for (int k0 = 0; k0 < 1024; k0 += 16) {
    float4 av4 = *(const float4*)&A[(size_t)(m0 + arow) * 1024 + k0 + akk];
    float4 bv4 = *(const float4*)&W[(size_t)(k0 + bkk) * 1024 + n0 + bcol];
    As[akk + 0][arow] = av4.x;
    As[akk + 1][arow] = av4.y;
    As[akk + 2][arow] = av4.z;
    As[akk + 3][arow] = av4.w;
    *(float4*)&Bs[bkk][bcol] = bv4;
    __syncthreads();
#pragma unroll
    for (int kk = 0; kk < 16; kk++) {
      float4 av = *(const float4*)&As[kk][ty * 4];
      float4 bv = *(const float4*)&Bs[kk][tx * 4];
      float a[4] = {av.x, av.y, av.z, av.w};
      float b[4] = {bv.x, bv.y, bv.z, bv.w};
#pragma unroll
      for (int i = 0; i < 4; i++)
#pragma unroll
        for (int j = 0; j < 4; j++) acc[i][j] += a[i] * b[j];
    }
    __syncthreads();
  }

#pragma unroll
  for (int i = 0; i < 4; i++) {
    int m = m0 + ty * 4 + i;
    int nbase = n0 + tx * 4;
    float4 o;
    o.x = acc[i][0] + bias[nbase + 0];
    o.y = acc[i][1] + bias[nbase + 1];
    o.z = acc[i][2] + bias[nbase + 2];
    o.w = acc[i][3] + bias[nbase + 3];
    if (RES) {
      float4 r4 = *(const float4*)&resid[(size_t)m * 1024 + nbase];
      o.x += r4.x; o.y += r4.y; o.z += r4.z; o.w += r4.w;
    }
    *(float4*)&out[(size_t)m * 1024 + nbase] = o;
  }
}

// ---------------------------------------------------------------------------
// Flash attention v2, fp32. Block = (bh, 64 q-rows), 256 threads (16x16).
// q,k,v,ctx row-major [M,1024]; head h occupies cols h*64..h*64+63.
// LDS: Qs[64][68] + KsT[64][68] (K transposed: [d][j]) + Vs[64][68]
//   = 52,224 B  (< 64 KB limit; R6's 69,632 B aborted at dispatch).
// Score tile 64x64 as 4x4/thread outer product; online softmax with 16-lane
// shuffle row-reductions; P stays in registers -- PV fetches P fragments via
// in-wave __shfl from the owning lane (row group = 16 lanes, same ty).
// ---------------------------------------------------------------------------
__global__ __launch_bounds__(256) void attn_flash(
    const float* __restrict__ q, const float* __restrict__ k,
    const float* __restrict__ v, float* __restrict__ ctx) {
  __shared__ __align__(16) float Qs[64][68];
  __shared__ __align__(16) float KsT[64][68];   // [d][j]
  __shared__ __align__(16) float Vs[64][68];    // [j][d]
  const int tid = threadIdx.x;
  const int tx = tid & 15, ty = tid >> 4;
  const int lane = tid & 63;
  const int srcbase = lane & 48;               // ty-group base within wave
  const int bh = blockIdx.y;                   // chunk-local b*16+h
  const int b = bh >> 4, h = bh & 15;
  const int q0 = blockIdx.x * 64;
  const size_t base = (size_t)b * S_ * H_ + h * 64;

  // ---- stage Q tile (64 rows x 64 floats), coalesced float4 ----
#pragma unroll
  for (int it = 0; it < 4; it++) {
    int flat = tid + 256 * it;                 // float4 index 0..1023
    int row = flat >> 4, dp = (flat & 15) * 4;
    *(float4*)&Qs[row][dp] =
        *(const float4*)&q[base + (size_t)(q0 + row) * H_ + dp];
  }

  float o[4][4];
  float mrow[4], lrow[4];
#pragma unroll
  for (int i = 0; i < 4; i++) {
    mrow[i] = -1e30f; lrow[i] = 0.f;
#pragma unroll
    for (int j = 0; j < 4; j++) o[i][j] = 0.f;
  }
  __syncthreads();

  for (int j0 = 0; j0 < S_; j0 += 64) {
    // ---- stage K (transposed) and V tiles ----
#pragma unroll
    for (int it = 0; it < 4; it++) {
      int flat = tid + 256 * it;
      int row = flat >> 4, dp = (flat & 15) * 4;  // row = j, dp = d
      float4 kv = *(const float4*)&k[base + (size_t)(j0 + row) * H_ + dp];
      KsT[dp + 0][row] = kv.x;
      KsT[dp + 1][row] = kv.y;
      KsT[dp + 2][row] = kv.z;
      KsT[dp + 3][row] = kv.w;
      *(float4*)&Vs[row][dp] =
          *(const float4*)&v[base + (size_t)(j0 + row) * H_ + dp];
    }
    __syncthreads();

    // ---- score tile: s[i][j] = sum_d Qs[ty4+i][d] * KsT[d][tx4+j] ----
    float s[4][4];
#pragma unroll
    for (int i = 0; i < 4; i++)
#pragma unroll
      for (int j = 0; j < 4; j++) s[i][j] = 0.f;
    for (int d = 0; d < 64; d += 4) {
      float4 qa[4], kb[4];
#pragma unroll
      for (int i = 0; i < 4; i++) qa[i] = *(const float4*)&Qs[ty * 4 + i][d];
#pragma unroll
      for (int u = 0; u < 4; u++) kb[u] = *(const float4*)&KsT[d + u][tx * 4];
#pragma unroll
      for (int i = 0; i < 4; i++) {
        s[i][0] += qa[i].x * kb[0].x + qa[i].y * kb[1].x +
                   qa[i].z * kb[2].x + qa[i].w * kb[3].x;
        s[i][1] += qa[i].x * kb[0].y + qa[i].y * kb[1].y +
                   qa[i].z * kb[2].y + qa[i].w * kb[3].y;
        s[i][2] += qa[i].x * kb[0].z + qa[i].y * kb[1].z +
                   qa[i].z * kb[2].z + qa[i].w * kb[3].z;
        s[i][3] += qa[i].x * kb[0].w + qa[i].y * kb[1].w +
                   qa[i].z * kb[2].w + qa[i].w * kb[3].w;
      }
    }

    // ---- bias: (s + pb)/8 - 0.1*dist ----
#pragma unroll
    for (int i = 0; i < 4; i++) {
      int qi = q0 + ty * 4 + i;
#pragma unroll
      for (int j = 0; j < 4; j++) {
        int jj = j0 + tx * 4 + j;
        float dist = fabsf((float)(qi - jj));
        float pb = __expf(-0.1f * fminf(dist, 5.0f));
        s[i][j] = (s[i][j] + pb) * 0.125f - 0.1f * dist;
      }
    }

    // ---- online softmax update (row = 16-lane group: xor 1,2,4,8) ----
#pragma unroll
    for (int i = 0; i < 4; i++) {
      float tm = fmaxf(fmaxf(s[i][0], s[i][1]), fmaxf(s[i][2], s[i][3]));
#pragma unroll
      for (int off = 1; off < 16; off <<= 1) tm = fmaxf(tm, __shfl_xor(tm, off));
      float mnew = fmaxf(mrow[i], tm);
      float alpha = __expf(mrow[i] - mnew);
      float rsum = 0.f;
#pragma unroll
      for (int j = 0; j < 4; j++) {
        s[i][j] = __expf(s[i][j] - mnew);   // s now holds P
        rsum += s[i][j];
      }
#pragma unroll
      for (int off = 1; off < 16; off <<= 1) rsum += __shfl_xor(rsum, off);
      lrow[i] = lrow[i] * alpha + rsum;
      mrow[i] = mnew;
#pragma unroll
      for (int j = 0; j < 4; j++) o[i][j] *= alpha;
    }

    // ---- PV: o[i][:] += sum_j P[row i][j] * V[j][:] ; P via in-wave shfl ----
    for (int jj = 0; jj < 64; jj += 4) {
      const int src = srcbase | (jj >> 2);   // lane owning P[., jj..jj+3]
      float4 v0 = *(const float4*)&Vs[jj + 0][tx * 4];
      float4 v1 = *(const float4*)&Vs[jj + 1][tx * 4];
      float4 v2 = *(const float4*)&Vs[jj + 2][tx * 4];
      float4 v3 = *(const float4*)&Vs[jj + 3][tx * 4];
#pragma unroll
      for (int i = 0; i < 4; i++) {
        float p0 = __shfl(s[i][0], src);
        float p1 = __shfl(s[i][1], src);
        float p2 = __shfl(s[i][2], src);
        float p3 = __shfl(s[i][3], src);
        o[i][0] += p0 * v0.x + p1 * v1.x + p2 * v2.x + p3 * v3.x;
        o[i][1] += p0 * v0.y + p1 * v1.y + p2 * v2.y + p3 * v3.y;
        o[i][2] += p0 * v0.z + p1 * v1.z + p2 * v2.z + p3 * v3.z;
        o[i][3] += p0 * v0.w + p1 * v1.w + p2 * v2.w + p3 * v3.w;
      }
    }
    __syncthreads();   // KsT/Vs reused next j-tile
  }

  // ---- normalize + write ctx ----
#pragma unroll
  for (int i = 0; i < 4; i++) {
    float inv = 1.0f / lrow[i];
    float4 ov = {o[i][0] * inv, o[i][1] * inv, o[i][2] * inv, o[i][3] * inv};
    *(float4*)&ctx[base + (size_t)(q0 + ty * 4 + i) * H_ + tx * 4] = ov;
  }
}

// ---------------------------------------------------------------------------
// LayerNorm over H=1024, one block per row, in-place safe
// ---------------------------------------------------------------------------
__global__ __launch_bounds__(256) void ln_kernel(
    const float* __restrict__ y, const float* __restrict__ g,
    const float* __restrict__ bta, float* __restrict__ yn) {
  const int row = blockIdx.x;
  const int tid = threadIdx.x, lane = tid & 63, wave = tid >> 6;
  const float* yr = y + (size_t)row * 1024;
  float vals[4], s = 0.f, s2 = 0.f;
#pragma unroll
  for (int i = 0; i < 4; i++) {
    float t = yr[tid + i * 256];
    vals[i] = t; s += t; s2 += t * t;
  }
#pragma unroll
  for (int off = 32; off; off >>= 1) {
    s += __shfl_xor(s, off);
    s2 += __shfl_xor(s2, off);
  }
  __shared__ float red[8];
  if (lane == 0) { red[wave] = s; red[4 + wave] = s2; }
  __syncthreads();
  s = red[0] + red[1] + red[2] + red[3];
  s2 = red[4] + red[5] + red[6] + red[7];
  float mu = s * (1.0f / 1024.0f);
  float var = s2 * (1.0f / 1024.0f) - mu * mu;
  float inv = rsqrtf(var + 1e-5f);
  float* ynr = yn + (size_t)row * 1024;
#pragma unroll
  for (int i = 0; i < 4; i++) {
    int hh = tid + i * 256;
    ynr[hh] = (vals[i] - mu) * inv * g[hh] + bta[hh];
  }
}

// ---------------------------------------------------------------------------
// Span logits: yn[M,1024] @ Ws[1024,9] + bs. One wave per row.
// ---------------------------------------------------------------------------
__global__ __launch_bounds__(256) void span_kernel(
    const float* __restrict__ yn, const float* __restrict__ Ws,
    const float* __restrict__ bs, float* __restrict__ logits) {
  const int tid = threadIdx.x, lane = tid & 63, wave = tid >> 6;
  const int row = blockIdx.x * 4 + wave;
  float local[9];
#pragma unroll
  for (int l = 0; l < 9; l++) local[l] = 0.f;
  const float* yr = yn + (size_t)row * 1024;
  for (int i = 0; i < 16; i++) {
    int hh = lane + i * 64;
    float yv = yr[hh];
#pragma unroll
    for (int l = 0; l < 9; l++) local[l] += yv * Ws[hh * 9 + l];
  }
#pragma unroll
  for (int l = 0; l < 9; l++) {
    float sv = local[l];
#pragma unroll
    for (int off = 32; off; off >>= 1) sv += __shfl_xor(sv, off);
    if (lane == 0) logits[(size_t)row * 9 + l] = sv + bs[l];
  }
}

// ---------------------------------------------------------------------------
// Entity-bias adjustment + FP32 output. One thread per token.
// ---------------------------------------------------------------------------
__global__ __launch_bounds__(256) void final_kernel(
    const float* __restrict__ logits, const float* __restrict__ eb,
    float* __restrict__ out) {
  const int m = blockIdx.x * 256 + threadIdx.x;  // chunk-local token
  const int i = m & 1023;                        // position within sequence
  float cur[9];
#pragma unroll
  for (int l = 0; l < 9; l++) cur[l] = logits[(size_t)m * 9 + l];
  if (i > 0) {
    const float* prev = logits + (size_t)(m - 1) * 9;
    int am = 0;
    float best = prev[0];
#pragma unroll
    for (int l = 1; l < 9; l++) {
      float pv = prev[l];
      if (pv > best) { best = pv; am = l; }  // strict > == first-max (jnp.argmax)
    }
    if (am == 1) cur[2] += 2.0f * eb[2];     // B_PERSON -> I_PERSON bias
  }
#pragma unroll
  for (int l = 0; l < 9; l++) out[(size_t)m * 9 + l] = cur[l];
}

// ---------------------------------------------------------------------------
extern "C" void kernel_launch(void* const* d_in, const int* in_sizes, int n_in,
                              void* d_out, int out_size, void* d_ws, size_t ws_size,
                              hipStream_t stream) {
  const float* x    = (const float*)d_in[0];
  const float* Wq   = (const float*)d_in[1];
  const float* bq   = (const float*)d_in[2];
  const float* Wk   = (const float*)d_in[3];
  const float* bk   = (const float*)d_in[4];
  const float* Wv   = (const float*)d_in[5];
  const float* bv   = (const float*)d_in[6];
  const float* Wo   = (const float*)d_in[7];
  const float* bo   = (const float*)d_in[8];
  const float* ln_g = (const float*)d_in[9];
  const float* ln_b = (const float*)d_in[10];
  const float* Ws   = (const float*)d_in[11];
  const float* bs   = (const float*)d_in[12];
  const float* eb   = (const float*)d_in[13];
  // d_in[14] = rel_pos_emb (unused by the forward math)
  float* out = (float*)d_out;       // output dtype fp32 (verified R5)
  float* ws = (float*)d_ws;

  const size_t PER_B = (size_t)S_ * H_;  // 1 Mi floats per buffer per batch
  int BC = 1;
  if (ws_size >= 4ull * 4 * PER_B * sizeof(float)) BC = 4;
  else if (ws_size >= 2ull * 4 * PER_B * sizeof(float)) BC = 2;

  for (int b0 = 0; b0 < 4; b0 += BC) {
    const size_t SZ = (size_t)BC * PER_B;
    float* q_ws   = ws;
    float* k_ws   = ws + SZ;
    float* v_ws   = ws + 2 * SZ;
    float* ctx_ws = ws + 3 * SZ;
    float* y_ws   = q_ws;    // q dead after attention
    float* lg_ws  = k_ws;    // k dead after attention

    const float* xb = x + (size_t)b0 * S_ * H_;
    const int M = BC * S_;

    dim3 gblk(16, M / 64);
    gemm_rm<0><<<gblk, 256, 0, stream>>>(xb, Wq, bq, nullptr, q_ws);
    gemm_rm<0><<<gblk, 256, 0, stream>>>(xb, Wk, bk, nullptr, k_ws);
    gemm_rm<0><<<gblk, 256, 0, stream>>>(xb, Wv, bv, nullptr, v_ws);
    attn_flash<<<dim3(S_ / 64, BC * NH_), 256, 0, stream>>>(q_ws, k_ws, v_ws, ctx_ws);
    gemm_rm<1><<<gblk, 256, 0, stream>>>(ctx_ws, Wo, bo, xb, y_ws);
    ln_kernel<<<M, 256, 0, stream>>>(y_ws, ln_g, ln_b, y_ws);
    span_kernel<<<M / 4, 256, 0, stream>>>(y_ws, Ws, bs, lg_ws);
    final_kernel<<<M / 256, 256, 0, stream>>>(lg_ws, eb, out + (size_t)b0 * S_ * L_);
  }
}

// Round 8
// 882.913 us; speedup vs baseline: 6.1553x; 1.1253x over previous
//
#include <hip/hip_runtime.h>
#include <hip/hip_bf16.h>
#include <math.h>

typedef __hip_bfloat16 bf16;
typedef __attribute__((ext_vector_type(8))) short frag16;   // 8 bf16 = 4 VGPRs
typedef __attribute__((ext_vector_type(4))) float f32x4;

#define S_   1024
#define H_   1024
#define NH_  16
#define D_   64
#define L_   9

__device__ __forceinline__ unsigned short bf16_rne(float x) {
  unsigned int b = __float_as_uint(x);
  b += 0x7FFFu + ((b >> 16) & 1u);
  return (unsigned short)(b >> 16);
}

// ---------------------------------------------------------------------------
// Split-bf16 MFMA GEMM: out[M,1024] = A[M,1024]@W[1024,1024] + bias (+resid).
// fp32 inputs are split in-register into bf16 hi/lo (x = xh + xl, xl holds
// the next 8 mantissa bits); acc += Ah*Bh + Ah*Bl + Al*Bh in fp32 MFMA
// accumulators -> ~2^-16 relative precision (comparable to fp32 reorder
// noise, safe for the downstream argmax). 3x MFMA passes at ~2 PF >> 157 TF
// fp32 vector ceiling.
// Block 256 thr = 4 waves; tile 64x64; BK=32; wave tile 32x32 = 2x2 mfma
// 16x16x32 tiles. Layouts (m89/m120-verified):
//   A-frag: A[m=lane&15][k=quad*8+j]   B-frag: B[k=quad*8+j][n=lane&15]
//   D: col=lane&15, row=quad*4+reg
// LDS: 4 x 64x40 bf16 = 20,480 B (pad 32->40 keeps b128 rows 16B-aligned).
// ---------------------------------------------------------------------------
template <int RES>
__global__ __launch_bounds__(256) void gemm_mfma(
    const float* __restrict__ A, const float* __restrict__ W,
    const float* __restrict__ bias, const float* __restrict__ resid,
    float* __restrict__ out) {
  __shared__ __align__(16) unsigned short Ah[64][40], Al[64][40];
  __shared__ __align__(16) unsigned short Bh[64][40], Bl[64][40];  // [n][k]
  const int tid = threadIdx.x;
  const int m0 = blockIdx.y * 64, n0 = blockIdx.x * 64;
  const int lane = tid & 63, wave = tid >> 6;
  const int wm = (wave >> 1) * 32, wn = (wave & 1) * 32;
  const int l15 = lane & 15, quad = lane >> 4;

  f32x4 acc[2][2];
#pragma unroll
  for (int i = 0; i < 2; i++)
#pragma unroll
    for (int j = 0; j < 2; j++) acc[i][j] = (f32x4){0.f, 0.f, 0.f, 0.f};

  for (int k0 = 0; k0 < 1024; k0 += 32) {
    // ---- stage: global fp32 -> split bf16 hi/lo -> LDS ----
#pragma unroll
    for (int it = 0; it < 2; it++) {
      const int f4 = tid + 256 * it;          // float4 index 0..511
      // A tile 64m x 32k
      const int arow = f4 >> 3, ak = (f4 & 7) * 4;
      float4 a4 = *(const float4*)&A[(size_t)(m0 + arow) * 1024 + k0 + ak];
      const float aa[4] = {a4.x, a4.y, a4.z, a4.w};
      unsigned short h[4], l[4];
#pragma unroll
      for (int c = 0; c < 4; c++) {
        h[c] = bf16_rne(aa[c]);
        float hi_f = __uint_as_float((unsigned int)h[c] << 16);
        l[c] = bf16_rne(aa[c] - hi_f);
      }
      *(uint2*)&Ah[arow][ak] =
          make_uint2((unsigned int)h[0] | ((unsigned int)h[1] << 16),
                     (unsigned int)h[2] | ((unsigned int)h[3] << 16));
      *(uint2*)&Al[arow][ak] =
          make_uint2((unsigned int)l[0] | ((unsigned int)l[1] << 16),
                     (unsigned int)l[2] | ((unsigned int)l[3] << 16));
      // W tile 32k x 64n, stored transposed [n][k]
      const int bk = f4 >> 4, bn = (f4 & 15) * 4;
      float4 w4 = *(const float4*)&W[(size_t)(k0 + bk) * 1024 + n0 + bn];
      const float ww[4] = {w4.x, w4.y, w4.z, w4.w};
#pragma unroll
      for (int c = 0; c < 4; c++) {
        unsigned short wh = bf16_rne(ww[c]);
        float hi_f = __uint_as_float((unsigned int)wh << 16);
        unsigned short wl = bf16_rne(ww[c] - hi_f);
        Bh[bn + c][bk] = wh;
        Bl[bn + c][bk] = wl;
      }
    }
    __syncthreads();

    // ---- fragments + 12 MFMA ----
    frag16 a_h[2], a_l[2], b_h[2], b_l[2];
#pragma unroll
    for (int s = 0; s < 2; s++) {
      const int row = wm + s * 16 + l15;
      a_h[s] = *(const frag16*)&Ah[row][quad * 8];
      a_l[s] = *(const frag16*)&Al[row][quad * 8];
      const int col = wn + s * 16 + l15;
      b_h[s] = *(const frag16*)&Bh[col][quad * 8];
      b_l[s] = *(const frag16*)&Bl[col][quad * 8];
    }
#pragma unroll
    for (int mi = 0; mi < 2; mi++)
#pragma unroll
      for (int ni = 0; ni < 2; ni++) {
        acc[mi][ni] = __builtin_amdgcn_mfma_f32_16x16x32_bf16(
            a_h[mi], b_h[ni], acc[mi][ni], 0, 0, 0);
        acc[mi][ni] = __builtin_amdgcn_mfma_f32_16x16x32_bf16(
            a_h[mi], b_l[ni], acc[mi][ni], 0, 0, 0);
        acc[mi][ni] = __builtin_amdgcn_mfma_f32_16x16x32_bf16(
            a_l[mi], b_h[ni], acc[mi][ni], 0, 0, 0);
      }
    __syncthreads();
  }

  // ---- epilogue: D row=quad*4+reg, col=lane&15 ----
#pragma unroll
  for (int mi = 0; mi < 2; mi++) {
    const int rbase = m0 + wm + mi * 16 + quad * 4;
#pragma unroll
    for (int ni = 0; ni < 2; ni++) {
      const int col = n0 + wn + ni * 16 + l15;
      const float bv = bias[col];
#pragma unroll
      for (int r = 0; r < 4; r++) {
        float val = acc[mi][ni][r] + bv;
        if (RES) val += resid[(size_t)(rbase + r) * 1024 + col];
        out[(size_t)(rbase + r) * 1024 + col] = val;
      }
    }
  }
}

// ---------------------------------------------------------------------------
// Flash attention v2, fp32 (unchanged from R7 pass: 494 us).
// ---------------------------------------------------------------------------
__global__ __launch_bounds__(256) void attn_flash(
    const float* __restrict__ q, const float* __restrict__ k,
    const float* __restrict__ v, float* __restrict__ ctx) {
  __shared__ __align__(16) float Qs[64][68];
  __shared__ __align__(16) float KsT[64][68];   // [d][j]
  __shared__ __align__(16) float Vs[64][68];    // [j][d]
  const int tid = threadIdx.x;
  const int tx = tid & 15, ty = tid >> 4;
  const int lane = tid & 63;
  const int srcbase = lane & 48;
  const int bh = blockIdx.y;
  const int b = bh >> 4, h = bh & 15;
  const int q0 = blockIdx.x * 64;
  const size_t base = (size_t)b * S_ * H_ + h * 64;

#pragma unroll
  for (int it = 0; it < 4; it++) {
    int flat = tid + 256 * it;
    int row = flat >> 4, dp = (flat & 15) * 4;
    *(float4*)&Qs[row][dp] =
        *(const float4*)&q[base + (size_t)(q0 + row) * H_ + dp];
  }

  float o[4][4];
  float mrow[4], lrow[4];
#pragma unroll
  for (int i = 0; i < 4; i++) {
    mrow[i] = -1e30f; lrow[i] = 0.f;
#pragma unroll
    for (int j = 0; j < 4; j++) o[i][j] = 0.f;
  }
  __syncthreads();

  for (int j0 = 0; j0 < S_; j0 += 64) {
#pragma unroll
    for (int it = 0; it < 4; it++) {
      int flat = tid + 256 * it;
      int row = flat >> 4, dp = (flat & 15) * 4;
      float4 kv = *(const float4*)&k[base + (size_t)(j0 + row) * H_ + dp];
      KsT[dp + 0][row] = kv.x;
      KsT[dp + 1][row] = kv.y;
      KsT[dp + 2][row] = kv.z;
      KsT[dp + 3][row] = kv.w;
      *(float4*)&Vs[row][dp] =
          *(const float4*)&v[base + (size_t)(j0 + row) * H_ + dp];
    }
    __syncthreads();

    float s[4][4];
#pragma unroll
    for (int i = 0; i < 4; i++)
#pragma unroll
      for (int j = 0; j < 4; j++) s[i][j] = 0.f;
    for (int d = 0; d < 64; d += 4) {
      float4 qa[4], kb[4];
#pragma unroll
      for (int i = 0; i < 4; i++) qa[i] = *(const float4*)&Qs[ty * 4 + i][d];
#pragma unroll
      for (int u = 0; u < 4; u++) kb[u] = *(const float4*)&KsT[d + u][tx * 4];
#pragma unroll
      for (int i = 0; i < 4; i++) {
        s[i][0] += qa[i].x * kb[0].x + qa[i].y * kb[1].x +
                   qa[i].z * kb[2].x + qa[i].w * kb[3].x;
        s[i][1] += qa[i].x * kb[0].y + qa[i].y * kb[1].y +
                   qa[i].z * kb[2].y + qa[i].w * kb[3].y;
        s[i][2] += qa[i].x * kb[0].z + qa[i].y * kb[1].z +
                   qa[i].z * kb[2].z + qa[i].w * kb[3].z;
        s[i][3] += qa[i].x * kb[0].w + qa[i].y * kb[1].w +
                   qa[i].z * kb[2].w + qa[i].w * kb[3].w;
      }
    }

#pragma unroll
    for (int i = 0; i < 4; i++) {
      int qi = q0 + ty * 4 + i;
#pragma unroll
      for (int j = 0; j < 4; j++) {
        int jj = j0 + tx * 4 + j;
        float dist = fabsf((float)(qi - jj));
        float pb = __expf(-0.1f * fminf(dist, 5.0f));
        s[i][j] = (s[i][j] + pb) * 0.125f - 0.1f * dist;
      }
    }

#pragma unroll
    for (int i = 0; i < 4; i++) {
      float tm = fmaxf(fmaxf(s[i][0], s[i][1]), fmaxf(s[i][2], s[i][3]));
#pragma unroll
      for (int off = 1; off < 16; off <<= 1) tm = fmaxf(tm, __shfl_xor(tm, off));
      float mnew = fmaxf(mrow[i], tm);
      float alpha = __expf(mrow[i] - mnew);
      float rsum = 0.f;
#pragma unroll
      for (int j = 0; j < 4; j++) {
        s[i][j] = __expf(s[i][j] - mnew);
        rsum += s[i][j];
      }
#pragma unroll
      for (int off = 1; off < 16; off <<= 1) rsum += __shfl_xor(rsum, off);
      lrow[i] = lrow[i] * alpha + rsum;
      mrow[i] = mnew;
#pragma unroll
      for (int j = 0; j < 4; j++) o[i][j] *= alpha;
    }

    for (int jj = 0; jj < 64; jj += 4) {
      const int src = srcbase | (jj >> 2);
      float4 v0 = *(const float4*)&Vs[jj + 0][tx * 4];
      float4 v1 = *(const float4*)&Vs[jj + 1][tx * 4];
      float4 v2 = *(const float4*)&Vs[jj + 2][tx * 4];
      float4 v3 = *(const float4*)&Vs[jj + 3][tx * 4];
#pragma unroll
      for (int i = 0; i < 4; i++) {
        float p0 = __shfl(s[i][0], src);
        float p1 = __shfl(s[i][1], src);
        float p2 = __shfl(s[i][2], src);
        float p3 = __shfl(s[i][3], src);
        o[i][0] += p0 * v0.x + p1 * v1.x + p2 * v2.x + p3 * v3.x;
        o[i][1] += p0 * v0.y + p1 * v1.y + p2 * v2.y + p3 * v3.y;
        o[i][2] += p0 * v0.z + p1 * v1.z + p2 * v2.z + p3 * v3.z;
        o[i][3] += p0 * v0.w + p1 * v1.w + p2 * v2.w + p3 * v3.w;
      }
    }
    __syncthreads();
  }

#pragma unroll
  for (int i = 0; i < 4; i++) {
    float inv = 1.0f / lrow[i];
    float4 ov = {o[i][0] * inv, o[i][1] * inv, o[i][2] * inv, o[i][3] * inv};
    *(float4*)&ctx[base + (size_t)(q0 + ty * 4 + i) * H_ + tx * 4] = ov;
  }
}

// ---------------------------------------------------------------------------
// LayerNorm over H=1024, one block per row, in-place safe
// ---------------------------------------------------------------------------
__global__ __launch_bounds__(256) void ln_kernel(
    const float* __restrict__ y, const float* __restrict__ g,
    const float* __restrict__ bta, float* __restrict__ yn) {
  const int row = blockIdx.x;
  const int tid = threadIdx.x, lane = tid & 63, wave = tid >> 6;
  const float* yr = y + (size_t)row * 1024;
  float vals[4], s = 0.f, s2 = 0.f;
#pragma unroll
  for (int i = 0; i < 4; i++) {
    float t = yr[tid + i * 256];
    vals[i] = t; s += t; s2 += t * t;
  }
#pragma unroll
  for (int off = 32; off; off >>= 1) {
    s += __shfl_xor(s, off);
    s2 += __shfl_xor(s2, off);
  }
  __shared__ float red[8];
  if (lane == 0) { red[wave] = s; red[4 + wave] = s2; }
  __syncthreads();
  s = red[0] + red[1] + red[2] + red[3];
  s2 = red[4] + red[5] + red[6] + red[7];
  float mu = s * (1.0f / 1024.0f);
  float var = s2 * (1.0f / 1024.0f) - mu * mu;
  float inv = rsqrtf(var + 1e-5f);
  float* ynr = yn + (size_t)row * 1024;
#pragma unroll
  for (int i = 0; i < 4; i++) {
    int hh = tid + i * 256;
    ynr[hh] = (vals[i] - mu) * inv * g[hh] + bta[hh];
  }
}

// ---------------------------------------------------------------------------
// Span logits: yn[M,1024] @ Ws[1024,9] + bs. One wave per row.
// ---------------------------------------------------------------------------
__global__ __launch_bounds__(256) void span_kernel(
    const float* __restrict__ yn, const float* __restrict__ Ws,
    const float* __restrict__ bs, float* __restrict__ logits) {
  const int tid = threadIdx.x, lane = tid & 63, wave = tid >> 6;
  const int row = blockIdx.x * 4 + wave;
  float local[9];
#pragma unroll
  for (int l = 0; l < 9; l++) local[l] = 0.f;
  const float* yr = yn + (size_t)row * 1024;
  for (int i = 0; i < 16; i++) {
    int hh = lane + i * 64;
    float yv = yr[hh];
#pragma unroll
    for (int l = 0; l < 9; l++) local[l] += yv * Ws[hh * 9 + l];
  }
#pragma unroll
  for (int l = 0; l < 9; l++) {
    float sv = local[l];
#pragma unroll
    for (int off = 32; off; off >>= 1) sv += __shfl_xor(sv, off);
    if (lane == 0) logits[(size_t)row * 9 + l] = sv + bs[l];
  }
}

// ---------------------------------------------------------------------------
// Entity-bias adjustment + FP32 output. One thread per token.
// ---------------------------------------------------------------------------
__global__ __launch_bounds__(256) void final_kernel(
    const float* __restrict__ logits, const float* __restrict__ eb,
    float* __restrict__ out) {
  const int m = blockIdx.x * 256 + threadIdx.x;
  const int i = m & 1023;
  float cur[9];
#pragma unroll
  for (int l = 0; l < 9; l++) cur[l] = logits[(size_t)m * 9 + l];
  if (i > 0) {
    const float* prev = logits + (size_t)(m - 1) * 9;
    int am = 0;
    float best = prev[0];
#pragma unroll
    for (int l = 1; l < 9; l++) {
      float pv = prev[l];
      if (pv > best) { best = pv; am = l; }
    }
    if (am == 1) cur[2] += 2.0f * eb[2];
  }
#pragma unroll
  for (int l = 0; l < 9; l++) out[(size_t)m * 9 + l] = cur[l];
}

// ---------------------------------------------------------------------------
extern "C" void kernel_launch(void* const* d_in, const int* in_sizes, int n_in,
                              void* d_out, int out_size, void* d_ws, size_t ws_size,
                              hipStream_t stream) {
  const float* x    = (const float*)d_in[0];
  const float* Wq   = (const float*)d_in[1];
  const float* bq   = (const float*)d_in[2];
  const float* Wk   = (const float*)d_in[3];
  const float* bk   = (const float*)d_in[4];
  const float* Wv   = (const float*)d_in[5];
  const float* bv   = (const float*)d_in[6];
  const float* Wo   = (const float*)d_in[7];
  const float* bo   = (const float*)d_in[8];
  const float* ln_g = (const float*)d_in[9];
  const float* ln_b = (const float*)d_in[10];
  const float* Ws   = (const float*)d_in[11];
  const float* bs   = (const float*)d_in[12];
  const float* eb   = (const float*)d_in[13];
  float* out = (float*)d_out;       // output dtype fp32 (verified R5)
  float* ws = (float*)d_ws;

  const size_t PER_B = (size_t)S_ * H_;
  int BC = 1;
  if (ws_size >= 4ull * 4 * PER_B * sizeof(float)) BC = 4;
  else if (ws_size >= 2ull * 4 * PER_B * sizeof(float)) BC = 2;

  for (int b0 = 0; b0 < 4; b0 += BC) {
    const size_t SZ = (size_t)BC * PER_B;
    float* q_ws   = ws;
    float* k_ws   = ws + SZ;
    float* v_ws   = ws + 2 * SZ;
    float* ctx_ws = ws + 3 * SZ;
    float* y_ws   = q_ws;    // q dead after attention
    float* lg_ws  = k_ws;    // k dead after attention

    const float* xb = x + (size_t)b0 * S_ * H_;
    const int M = BC * S_;

    dim3 gblk(16, M / 64);
    gemm_mfma<0><<<gblk, 256, 0, stream>>>(xb, Wq, bq, nullptr, q_ws);
    gemm_mfma<0><<<gblk, 256, 0, stream>>>(xb, Wk, bk, nullptr, k_ws);
    gemm_mfma<0><<<gblk, 256, 0, stream>>>(xb, Wv, bv, nullptr, v_ws);
    attn_flash<<<dim3(S_ / 64, BC * NH_), 256, 0, stream>>>(q_ws, k_ws, v_ws, ctx_ws);
    gemm_mfma<1><<<gblk, 256, 0, stream>>>(ctx_ws, Wo, bo, xb, y_ws);
    ln_kernel<<<M, 256, 0, stream>>>(y_ws, ln_g, ln_b, y_ws);
    span_kernel<<<M / 4, 256, 0, stream>>>(y_ws, Ws, bs, lg_ws);
    final_kernel<<<M / 256, 256, 0, stream>>>(lg_ws, eb, out + (size_t)b0 * S_ * L_);
  }
}

// Round 9
// 581.744 us; speedup vs baseline: 9.3420x; 1.5177x over previous
//
#include <hip/hip_runtime.h>
#include <hip/hip_bf16.h>
#include <math.h>

typedef __hip_bfloat16 bf16;
typedef __attribute__((ext_vector_type(8))) short frag16;   // 8 bf16 = 4 VGPRs
typedef __attribute__((ext_vector_type(4))) float f32x4;

#define S_   1024
#define H_   1024
#define NH_  16
#define D_   64
#define L_   9

__device__ __forceinline__ unsigned short bf16_rne(float x) {
  unsigned int b = __float_as_uint(x);
  b += 0x7FFFu + ((b >> 16) & 1u);
  return (unsigned short)(b >> 16);
}

// ---------------------------------------------------------------------------
// Split-bf16 MFMA GEMM (verified R8). out = A@W + bias (+resid).
// ---------------------------------------------------------------------------
template <int RES>
__global__ __launch_bounds__(256) void gemm_mfma(
    const float* __restrict__ A, const float* __restrict__ W,
    const float* __restrict__ bias, const float* __restrict__ resid,
    float* __restrict__ out) {
  __shared__ __align__(16) unsigned short Ah[64][40], Al[64][40];
  __shared__ __align__(16) unsigned short Bh[64][40], Bl[64][40];  // [n][k]
  const int tid = threadIdx.x;
  const int m0 = blockIdx.y * 64, n0 = blockIdx.x * 64;
  const int lane = tid & 63, wave = tid >> 6;
  const int wm = (wave >> 1) * 32, wn = (wave & 1) * 32;
  const int l15 = lane & 15, quad = lane >> 4;

  f32x4 acc[2][2];
#pragma unroll
  for (int i = 0; i < 2; i++)
#pragma unroll
    for (int j = 0; j < 2; j++) acc[i][j] = (f32x4){0.f, 0.f, 0.f, 0.f};

  for (int k0 = 0; k0 < 1024; k0 += 32) {
#pragma unroll
    for (int it = 0; it < 2; it++) {
      const int f4 = tid + 256 * it;
      const int arow = f4 >> 3, ak = (f4 & 7) * 4;
      float4 a4 = *(const float4*)&A[(size_t)(m0 + arow) * 1024 + k0 + ak];
      const float aa[4] = {a4.x, a4.y, a4.z, a4.w};
      unsigned short h[4], l[4];
#pragma unroll
      for (int c = 0; c < 4; c++) {
        h[c] = bf16_rne(aa[c]);
        float hi_f = __uint_as_float((unsigned int)h[c] << 16);
        l[c] = bf16_rne(aa[c] - hi_f);
      }
      *(uint2*)&Ah[arow][ak] =
          make_uint2((unsigned int)h[0] | ((unsigned int)h[1] << 16),
                     (unsigned int)h[2] | ((unsigned int)h[3] << 16));
      *(uint2*)&Al[arow][ak] =
          make_uint2((unsigned int)l[0] | ((unsigned int)l[1] << 16),
                     (unsigned int)l[2] | ((unsigned int)l[3] << 16));
      const int bk = f4 >> 4, bn = (f4 & 15) * 4;
      float4 w4 = *(const float4*)&W[(size_t)(k0 + bk) * 1024 + n0 + bn];
      const float ww[4] = {w4.x, w4.y, w4.z, w4.w};
#pragma unroll
      for (int c = 0; c < 4; c++) {
        unsigned short wh = bf16_rne(ww[c]);
        float hi_f = __uint_as_float((unsigned int)wh << 16);
        unsigned short wl = bf16_rne(ww[c] - hi_f);
        Bh[bn + c][bk] = wh;
        Bl[bn + c][bk] = wl;
      }
    }
    __syncthreads();

    frag16 a_h[2], a_l[2], b_h[2], b_l[2];
#pragma unroll
    for (int s = 0; s < 2; s++) {
      const int row = wm + s * 16 + l15;
      a_h[s] = *(const frag16*)&Ah[row][quad * 8];
      a_l[s] = *(const frag16*)&Al[row][quad * 8];
      const int col = wn + s * 16 + l15;
      b_h[s] = *(const frag16*)&Bh[col][quad * 8];
      b_l[s] = *(const frag16*)&Bl[col][quad * 8];
    }
#pragma unroll
    for (int mi = 0; mi < 2; mi++)
#pragma unroll
      for (int ni = 0; ni < 2; ni++) {
        acc[mi][ni] = __builtin_amdgcn_mfma_f32_16x16x32_bf16(
            a_h[mi], b_h[ni], acc[mi][ni], 0, 0, 0);
        acc[mi][ni] = __builtin_amdgcn_mfma_f32_16x16x32_bf16(
            a_h[mi], b_l[ni], acc[mi][ni], 0, 0, 0);
        acc[mi][ni] = __builtin_amdgcn_mfma_f32_16x16x32_bf16(
            a_l[mi], b_h[ni], acc[mi][ni], 0, 0, 0);
      }
    __syncthreads();
  }

#pragma unroll
  for (int mi = 0; mi < 2; mi++) {
    const int rbase = m0 + wm + mi * 16 + quad * 4;
#pragma unroll
    for (int ni = 0; ni < 2; ni++) {
      const int col = n0 + wn + ni * 16 + l15;
      const float bv = bias[col];
#pragma unroll
      for (int r = 0; r < 4; r++) {
        float val = acc[mi][ni][r] + bv;
        if (RES) val += resid[(size_t)(rbase + r) * 1024 + col];
        out[(size_t)(rbase + r) * 1024 + col] = val;
      }
    }
  }
}

// ---------------------------------------------------------------------------
// MFMA flash attention. Block = (bh, 64 q-rows), 4 waves; wave w owns q-rows
// [16w,16w+16) -> softmax rows stay in-wave. Per 64-j tile:
//   stage K hi/lo [j][d] + V^T [d][j] (bf16, rows padded to 72 shorts=144B:
//   16-row frag reads 2-way aliased = free; 16B-aligned for ds_read_b128),
//   S = Qh*Kh + Ql*Kh + Qh*Kl (split-bf16, ~2^-16 rel err),
//   online softmax in C-layout regs (row=quad*4+reg, col=l15; m89 mapping),
//   P (plain bf16) -> Pst (own rows only: no barrier, same-wave lgkm order),
//   PV: P A-frags x V^T B-frags, 8 MFMA. 2 barriers/tile.
// LDS 4*9216 = 36864 B -> 4 blocks/CU.
// ---------------------------------------------------------------------------
__global__ __launch_bounds__(256) void attn_flash_mfma(
    const float* __restrict__ q, const float* __restrict__ k,
    const float* __restrict__ v, float* __restrict__ ctx) {
  __shared__ __align__(16) unsigned short Kh[64][72], Kl[64][72];
  __shared__ __align__(16) unsigned short VT[64][72];   // [d][j]
  __shared__ __align__(16) unsigned short Pst[64][72];  // [m][j]
  const int tid = threadIdx.x;
  const int lane = tid & 63, wave = tid >> 6;
  const int l15 = lane & 15, quad = lane >> 4;
  const int w16 = wave * 16;
  const int bh = blockIdx.y;
  const int b = bh >> 4, h = bh & 15;
  const int q0 = blockIdx.x * 64;
  const size_t base = (size_t)b * S_ * H_ + h * 64;

  // ---- stage Q hi/lo into Kh/Kl, then lift this wave's A-frags ----
#pragma unroll
  for (int it = 0; it < 4; it++) {
    const int flat = tid + 256 * it;
    const int row = flat >> 4, dp = (flat & 15) * 4;
    float4 a4 = *(const float4*)&q[base + (size_t)(q0 + row) * H_ + dp];
    const float aa[4] = {a4.x, a4.y, a4.z, a4.w};
    unsigned short hh[4], ll[4];
#pragma unroll
    for (int c = 0; c < 4; c++) {
      hh[c] = bf16_rne(aa[c]);
      float hi_f = __uint_as_float((unsigned int)hh[c] << 16);
      ll[c] = bf16_rne(aa[c] - hi_f);
    }
    *(uint2*)&Kh[row][dp] =
        make_uint2((unsigned int)hh[0] | ((unsigned int)hh[1] << 16),
                   (unsigned int)hh[2] | ((unsigned int)hh[3] << 16));
    *(uint2*)&Kl[row][dp] =
        make_uint2((unsigned int)ll[0] | ((unsigned int)ll[1] << 16),
                   (unsigned int)ll[2] | ((unsigned int)ll[3] << 16));
  }
  __syncthreads();
  frag16 a_h[2], a_l[2];
#pragma unroll
  for (int kk = 0; kk < 2; kk++) {
    a_h[kk] = *(const frag16*)&Kh[w16 + l15][kk * 32 + quad * 8];
    a_l[kk] = *(const frag16*)&Kl[w16 + l15][kk * 32 + quad * 8];
  }

  f32x4 o[4];
  float mrow[4], lrow[4];
#pragma unroll
  for (int i = 0; i < 4; i++) {
    o[i] = (f32x4){0.f, 0.f, 0.f, 0.f};
    mrow[i] = -1e30f; lrow[i] = 0.f;
  }

  for (int j0 = 0; j0 < S_; j0 += 64) {
    __syncthreads();   // prior reads of Kh/Kl/VT done (also covers Q-frag lift)
    // ---- stage K hi/lo + V^T ----
#pragma unroll
    for (int it = 0; it < 4; it++) {
      const int flat = tid + 256 * it;
      const int row = flat >> 4, dp = (flat & 15) * 4;
      float4 kv = *(const float4*)&k[base + (size_t)(j0 + row) * H_ + dp];
      const float kka[4] = {kv.x, kv.y, kv.z, kv.w};
      unsigned short hh[4], ll[4];
#pragma unroll
      for (int c = 0; c < 4; c++) {
        hh[c] = bf16_rne(kka[c]);
        float hi_f = __uint_as_float((unsigned int)hh[c] << 16);
        ll[c] = bf16_rne(kka[c] - hi_f);
      }
      *(uint2*)&Kh[row][dp] =
          make_uint2((unsigned int)hh[0] | ((unsigned int)hh[1] << 16),
                     (unsigned int)hh[2] | ((unsigned int)hh[3] << 16));
      *(uint2*)&Kl[row][dp] =
          make_uint2((unsigned int)ll[0] | ((unsigned int)ll[1] << 16),
                     (unsigned int)ll[2] | ((unsigned int)ll[3] << 16));
      float4 vv = *(const float4*)&v[base + (size_t)(j0 + row) * H_ + dp];
      VT[dp + 0][row] = bf16_rne(vv.x);
      VT[dp + 1][row] = bf16_rne(vv.y);
      VT[dp + 2][row] = bf16_rne(vv.z);
      VT[dp + 3][row] = bf16_rne(vv.w);
    }
    __syncthreads();

    // ---- S = Q.K^T (split x3) ----
    f32x4 c4[4];
#pragma unroll
    for (int nt = 0; nt < 4; nt++) c4[nt] = (f32x4){0.f, 0.f, 0.f, 0.f};
#pragma unroll
    for (int kk = 0; kk < 2; kk++) {
#pragma unroll
      for (int nt = 0; nt < 4; nt++) {
        frag16 bh_ = *(const frag16*)&Kh[nt * 16 + l15][kk * 32 + quad * 8];
        frag16 bl_ = *(const frag16*)&Kl[nt * 16 + l15][kk * 32 + quad * 8];
        c4[nt] = __builtin_amdgcn_mfma_f32_16x16x32_bf16(a_h[kk], bh_, c4[nt], 0, 0, 0);
        c4[nt] = __builtin_amdgcn_mfma_f32_16x16x32_bf16(a_l[kk], bh_, c4[nt], 0, 0, 0);
        c4[nt] = __builtin_amdgcn_mfma_f32_16x16x32_bf16(a_h[kk], bl_, c4[nt], 0, 0, 0);
      }
    }

    // ---- bias + online softmax + P store ----
    // far tiles (|q0-j0|>=68): dist>5 everywhere -> pb = exp(-0.5) const
    const bool far = (j0 >= q0 + 68) || (q0 >= j0 + 68);
#pragma unroll
    for (int r = 0; r < 4; r++) {
      const int qi = q0 + w16 + quad * 4 + r;
      float sv[4];
#pragma unroll
      for (int nt = 0; nt < 4; nt++) {
        const int jj = j0 + nt * 16 + l15;
        const float dist = fabsf((float)(qi - jj));
        const float pb = far ? 0.60653066f : __expf(-0.1f * fminf(dist, 5.0f));
        sv[nt] = (c4[nt][r] + pb) * 0.125f - 0.1f * dist;
      }
      float tm = fmaxf(fmaxf(sv[0], sv[1]), fmaxf(sv[2], sv[3]));
#pragma unroll
      for (int off = 1; off < 16; off <<= 1) tm = fmaxf(tm, __shfl_xor(tm, off));
      const float mnew = fmaxf(mrow[r], tm);
      const float alpha = __expf(mrow[r] - mnew);
      float rs = 0.f;
#pragma unroll
      for (int nt = 0; nt < 4; nt++) {
        sv[nt] = __expf(sv[nt] - mnew);
        rs += sv[nt];
      }
#pragma unroll
      for (int off = 1; off < 16; off <<= 1) rs += __shfl_xor(rs, off);
      lrow[r] = lrow[r] * alpha + rs;
      mrow[r] = mnew;
#pragma unroll
      for (int dt = 0; dt < 4; dt++) o[dt][r] *= alpha;
#pragma unroll
      for (int nt = 0; nt < 4; nt++)
        Pst[w16 + quad * 4 + r][nt * 16 + l15] = bf16_rne(sv[nt]);
    }

    // ---- PV: own-rows only; same-wave LDS ordering (no barrier) ----
    frag16 pa[2];
#pragma unroll
    for (int kk = 0; kk < 2; kk++)
      pa[kk] = *(const frag16*)&Pst[w16 + l15][kk * 32 + quad * 8];
#pragma unroll
    for (int dt = 0; dt < 4; dt++) {
      frag16 vb0 = *(const frag16*)&VT[dt * 16 + l15][quad * 8];
      frag16 vb1 = *(const frag16*)&VT[dt * 16 + l15][32 + quad * 8];
      o[dt] = __builtin_amdgcn_mfma_f32_16x16x32_bf16(pa[0], vb0, o[dt], 0, 0, 0);
      o[dt] = __builtin_amdgcn_mfma_f32_16x16x32_bf16(pa[1], vb1, o[dt], 0, 0, 0);
    }
  }

  // ---- normalize + write ctx ----
#pragma unroll
  for (int r = 0; r < 4; r++) {
    const float inv = 1.0f / lrow[r];
    const size_t rowp = base + (size_t)(q0 + w16 + quad * 4 + r) * H_;
#pragma unroll
    for (int dt = 0; dt < 4; dt++)
      ctx[rowp + dt * 16 + l15] = o[dt][r] * inv;
  }
}

// ---------------------------------------------------------------------------
// LayerNorm over H=1024, one block per row, in-place safe
// ---------------------------------------------------------------------------
__global__ __launch_bounds__(256) void ln_kernel(
    const float* __restrict__ y, const float* __restrict__ g,
    const float* __restrict__ bta, float* __restrict__ yn) {
  const int row = blockIdx.x;
  const int tid = threadIdx.x, lane = tid & 63, wave = tid >> 6;
  const float* yr = y + (size_t)row * 1024;
  float vals[4], s = 0.f, s2 = 0.f;
#pragma unroll
  for (int i = 0; i < 4; i++) {
    float t = yr[tid + i * 256];
    vals[i] = t; s += t; s2 += t * t;
  }
#pragma unroll
  for (int off = 32; off; off >>= 1) {
    s += __shfl_xor(s, off);
    s2 += __shfl_xor(s2, off);
  }
  __shared__ float red[8];
  if (lane == 0) { red[wave] = s; red[4 + wave] = s2; }
  __syncthreads();
  s = red[0] + red[1] + red[2] + red[3];
  s2 = red[4] + red[5] + red[6] + red[7];
  float mu = s * (1.0f / 1024.0f);
  float var = s2 * (1.0f / 1024.0f) - mu * mu;
  float inv = rsqrtf(var + 1e-5f);
  float* ynr = yn + (size_t)row * 1024;
#pragma unroll
  for (int i = 0; i < 4; i++) {
    int hh = tid + i * 256;
    ynr[hh] = (vals[i] - mu) * inv * g[hh] + bta[hh];
  }
}

// ---------------------------------------------------------------------------
// Span logits: yn[M,1024] @ Ws[1024,9] + bs. One wave per row.
// ---------------------------------------------------------------------------
__global__ __launch_bounds__(256) void span_kernel(
    const float* __restrict__ yn, const float* __restrict__ Ws,
    const float* __restrict__ bs, float* __restrict__ logits) {
  const int tid = threadIdx.x, lane = tid & 63, wave = tid >> 6;
  const int row = blockIdx.x * 4 + wave;
  float local[9];
#pragma unroll
  for (int l = 0; l < 9; l++) local[l] = 0.f;
  const float* yr = yn + (size_t)row * 1024;
  for (int i = 0; i < 16; i++) {
    int hh = lane + i * 64;
    float yv = yr[hh];
#pragma unroll
    for (int l = 0; l < 9; l++) local[l] += yv * Ws[hh * 9 + l];
  }
#pragma unroll
  for (int l = 0; l < 9; l++) {
    float sv = local[l];
#pragma unroll
    for (int off = 32; off; off >>= 1) sv += __shfl_xor(sv, off);
    if (lane == 0) logits[(size_t)row * 9 + l] = sv + bs[l];
  }
}

// ---------------------------------------------------------------------------
// Entity-bias adjustment + FP32 output. One thread per token.
// ---------------------------------------------------------------------------
__global__ __launch_bounds__(256) void final_kernel(
    const float* __restrict__ logits, const float* __restrict__ eb,
    float* __restrict__ out) {
  const int m = blockIdx.x * 256 + threadIdx.x;
  const int i = m & 1023;
  float cur[9];
#pragma unroll
  for (int l = 0; l < 9; l++) cur[l] = logits[(size_t)m * 9 + l];
  if (i > 0) {
    const float* prev = logits + (size_t)(m - 1) * 9;
    int am = 0;
    float best = prev[0];
#pragma unroll
    for (int l = 1; l < 9; l++) {
      float pv = prev[l];
      if (pv > best) { best = pv; am = l; }
    }
    if (am == 1) cur[2] += 2.0f * eb[2];
  }
#pragma unroll
  for (int l = 0; l < 9; l++) out[(size_t)m * 9 + l] = cur[l];
}

// ---------------------------------------------------------------------------
extern "C" void kernel_launch(void* const* d_in, const int* in_sizes, int n_in,
                              void* d_out, int out_size, void* d_ws, size_t ws_size,
                              hipStream_t stream) {
  const float* x    = (const float*)d_in[0];
  const float* Wq   = (const float*)d_in[1];
  const float* bq   = (const float*)d_in[2];
  const float* Wk   = (const float*)d_in[3];
  const float* bk   = (const float*)d_in[4];
  const float* Wv   = (const float*)d_in[5];
  const float* bv   = (const float*)d_in[6];
  const float* Wo   = (const float*)d_in[7];
  const float* bo   = (const float*)d_in[8];
  const float* ln_g = (const float*)d_in[9];
  const float* ln_b = (const float*)d_in[10];
  const float* Ws   = (const float*)d_in[11];
  const float* bs   = (const float*)d_in[12];
  const float* eb   = (const float*)d_in[13];
  float* out = (float*)d_out;       // output dtype fp32 (verified R5)
  float* ws = (float*)d_ws;

  const size_t PER_B = (size_t)S_ * H_;
  int BC = 1;
  if (ws_size >= 4ull * 4 * PER_B * sizeof(float)) BC = 4;
  else if (ws_size >= 2ull * 4 * PER_B * sizeof(float)) BC = 2;

  for (int b0 = 0; b0 < 4; b0 += BC) {
    const size_t SZ = (size_t)BC * PER_B;
    float* q_ws   = ws;
    float* k_ws   = ws + SZ;
    float* v_ws   = ws + 2 * SZ;
    float* ctx_ws = ws + 3 * SZ;
    float* y_ws   = q_ws;    // q dead after attention
    float* lg_ws  = k_ws;    // k dead after attention

    const float* xb = x + (size_t)b0 * S_ * H_;
    const int M = BC * S_;

    dim3 gblk(16, M / 64);
    gemm_mfma<0><<<gblk, 256, 0, stream>>>(xb, Wq, bq, nullptr, q_ws);
    gemm_mfma<0><<<gblk, 256, 0, stream>>>(xb, Wk, bk, nullptr, k_ws);
    gemm_mfma<0><<<gblk, 256, 0, stream>>>(xb, Wv, bv, nullptr, v_ws);
    attn_flash_mfma<<<dim3(S_ / 64, BC * NH_), 256, 0, stream>>>(q_ws, k_ws, v_ws, ctx_ws);
    gemm_mfma<1><<<gblk, 256, 0, stream>>>(ctx_ws, Wo, bo, xb, y_ws);
    ln_kernel<<<M, 256, 0, stream>>>(y_ws, ln_g, ln_b, y_ws);
    span_kernel<<<M / 4, 256, 0, stream>>>(y_ws, Ws, bs, lg_ws);
    final_kernel<<<M / 256, 256, 0, stream>>>(lg_ws, eb, out + (size_t)b0 * S_ * L_);
  }
}

// Round 10
// 379.333 us; speedup vs baseline: 14.3268x; 1.5336x over previous
//
#include <hip/hip_runtime.h>
#include <hip/hip_bf16.h>
#include <math.h>

typedef unsigned short ush;
typedef __attribute__((ext_vector_type(8))) short frag16;   // 8 bf16 = 4 VGPRs
typedef __attribute__((ext_vector_type(4))) float f32x4;

#define S_   1024
#define H_   1024
#define NH_  16
#define D_   64
#define L_   9
#define MB_  (1048576ull)

__device__ __forceinline__ ush bf16_rne(float x) {
  unsigned int b = __float_as_uint(x);
  b += 0x7FFFu + ((b >> 16) & 1u);
  return (ush)(b >> 16);
}
__device__ __forceinline__ void split2(float x, ush& h, ush& l) {
  h = bf16_rne(x);
  l = bf16_rne(x - __uint_as_float((unsigned int)h << 16));
}

// ---------------------------------------------------------------------------
// Split + transpose 4 weights in one launch. W [k][n] fp32 -> WTh/WTl [n][k]
// bf16. Grid (16,16,4).
// ---------------------------------------------------------------------------
__global__ __launch_bounds__(256) void split_wT4(
    const float* W0, const float* W1, const float* W2, const float* W3,
    ush* h0, ush* l0, ush* h1, ush* l1, ush* h2, ush* l2, ush* h3, ush* l3) {
  __shared__ __align__(16) float Ls[64][68];
  const float* W = (blockIdx.z == 0) ? W0 : (blockIdx.z == 1) ? W1
                 : (blockIdx.z == 2) ? W2 : W3;
  ush* Th = (blockIdx.z == 0) ? h0 : (blockIdx.z == 1) ? h1
          : (blockIdx.z == 2) ? h2 : h3;
  ush* Tl = (blockIdx.z == 0) ? l0 : (blockIdx.z == 1) ? l1
          : (blockIdx.z == 2) ? l2 : l3;
  const int tid = threadIdx.x;
  const int n0 = blockIdx.x * 64, k0 = blockIdx.y * 64;
#pragma unroll
  for (int it = 0; it < 4; it++) {
    int flat = tid + 256 * it;              // 1024 float4s: 64k x 16 chunks
    int row = flat >> 4, nc = (flat & 15) * 4;
    *(float4*)&Ls[row][nc] = *(const float4*)&W[(size_t)(k0 + row) * 1024 + n0 + nc];
  }
  __syncthreads();
#pragma unroll
  for (int it = 0; it < 2; it++) {
    int flat = tid + 256 * it;              // 512: 64n x 8 k-chunks
    int nrow = flat >> 3, kc = (flat & 7) * 8;
    ush hs[8], ls[8];
#pragma unroll
    for (int u = 0; u < 8; u++) split2(Ls[kc + u][nrow], hs[u], ls[u]);
    uint4 ph, pl;
    ph.x = hs[0] | ((unsigned)hs[1] << 16); ph.y = hs[2] | ((unsigned)hs[3] << 16);
    ph.z = hs[4] | ((unsigned)hs[5] << 16); ph.w = hs[6] | ((unsigned)hs[7] << 16);
    pl.x = ls[0] | ((unsigned)ls[1] << 16); pl.y = ls[2] | ((unsigned)ls[3] << 16);
    pl.z = ls[4] | ((unsigned)ls[5] << 16); pl.w = ls[6] | ((unsigned)ls[7] << 16);
    size_t o = (size_t)(n0 + nrow) * 1024 + k0 + kc;
    *(uint4*)&Th[o] = ph;
    *(uint4*)&Tl[o] = pl;
  }
}

// ---------------------------------------------------------------------------
// Split-bf16 MFMA GEMM, pre-split B [n][k]. 64x64 tile, BK=32, 4 waves of
// 32x32 (2x2 16x16x32 frags), 3-term split product (R8-verified layouts).
// ASPLIT: 0 = A fp32 [m][1024] split in-loop; 1 = A pre-split bf16 (copy).
// EP: 0 = write hi/lo bf16 [bh][s][d] + bias (q,k)
//     1 = write bf16 [bh][s][d] + bias (v)
//     2 = write fp32 [m][n] + bias + fp32 residual (o-proj)
// ---------------------------------------------------------------------------
template <int ASPLIT, int EP>
__global__ __launch_bounds__(256) void gemm_bf(
    const float* __restrict__ Af,
    const ush* __restrict__ Abh, const ush* __restrict__ Abl,
    const ush* __restrict__ Bgh, const ush* __restrict__ Bgl,
    const float* __restrict__ bias, const float* __restrict__ resid,
    float* __restrict__ outf, ush* __restrict__ oh, ush* __restrict__ ol) {
  __shared__ __align__(16) ush Ah[64][40], Al[64][40];
  __shared__ __align__(16) ush Bh[64][40], Bl[64][40];   // [n][k]
  const int tid = threadIdx.x;
  const int m0 = blockIdx.y * 64, n0 = blockIdx.x * 64;
  const int lane = tid & 63, wave = tid >> 6;
  const int wm = (wave >> 1) * 32, wn = (wave & 1) * 32;
  const int l15 = lane & 15, quad = lane >> 4;

  f32x4 acc[2][2];
#pragma unroll
  for (int i = 0; i < 2; i++)
#pragma unroll
    for (int j = 0; j < 2; j++) acc[i][j] = (f32x4){0.f, 0.f, 0.f, 0.f};

  for (int k0 = 0; k0 < 1024; k0 += 32) {
    if (ASPLIT == 0) {
#pragma unroll
      for (int it = 0; it < 2; it++) {
        const int f4 = tid + 256 * it;
        const int arow = f4 >> 3, ak = (f4 & 7) * 4;
        float4 a4 = *(const float4*)&Af[(size_t)(m0 + arow) * 1024 + k0 + ak];
        const float aa[4] = {a4.x, a4.y, a4.z, a4.w};
        ush h[4], l[4];
#pragma unroll
        for (int c = 0; c < 4; c++) split2(aa[c], h[c], l[c]);
        *(uint2*)&Ah[arow][ak] =
            make_uint2((unsigned)h[0] | ((unsigned)h[1] << 16),
                       (unsigned)h[2] | ((unsigned)h[3] << 16));
        *(uint2*)&Al[arow][ak] =
            make_uint2((unsigned)l[0] | ((unsigned)l[1] << 16),
                       (unsigned)l[2] | ((unsigned)l[3] << 16));
      }
    } else {
      const int row = tid >> 2, kc = (tid & 3) * 8;
      const size_t ga = (size_t)(m0 + row) * 1024 + k0 + kc;
      *(uint4*)&Ah[row][kc] = *(const uint4*)&Abh[ga];
      *(uint4*)&Al[row][kc] = *(const uint4*)&Abl[ga];
    }
    {
      const int row = tid >> 2, kc = (tid & 3) * 8;
      const size_t gb = (size_t)(n0 + row) * 1024 + k0 + kc;
      *(uint4*)&Bh[row][kc] = *(const uint4*)&Bgh[gb];
      *(uint4*)&Bl[row][kc] = *(const uint4*)&Bgl[gb];
    }
    __syncthreads();

    frag16 a_h[2], a_l[2], b_h[2], b_l[2];
#pragma unroll
    for (int s = 0; s < 2; s++) {
      const int row = wm + s * 16 + l15;
      a_h[s] = *(const frag16*)&Ah[row][quad * 8];
      a_l[s] = *(const frag16*)&Al[row][quad * 8];
      const int col = wn + s * 16 + l15;
      b_h[s] = *(const frag16*)&Bh[col][quad * 8];
      b_l[s] = *(const frag16*)&Bl[col][quad * 8];
    }
#pragma unroll
    for (int mi = 0; mi < 2; mi++)
#pragma unroll
      for (int ni = 0; ni < 2; ni++) {
        acc[mi][ni] = __builtin_amdgcn_mfma_f32_16x16x32_bf16(
            a_h[mi], b_h[ni], acc[mi][ni], 0, 0, 0);
        acc[mi][ni] = __builtin_amdgcn_mfma_f32_16x16x32_bf16(
            a_h[mi], b_l[ni], acc[mi][ni], 0, 0, 0);
        acc[mi][ni] = __builtin_amdgcn_mfma_f32_16x16x32_bf16(
            a_l[mi], b_h[ni], acc[mi][ni], 0, 0, 0);
      }
    __syncthreads();
  }

#pragma unroll
  for (int mi = 0; mi < 2; mi++) {
    const int rbase = m0 + wm + mi * 16 + quad * 4;
#pragma unroll
    for (int ni = 0; ni < 2; ni++) {
      const int col = n0 + wn + ni * 16 + l15;
      const float bv = bias[col];
      const int hidx = col >> 6, d = col & 63;
#pragma unroll
      for (int r = 0; r < 4; r++) {
        const int m = rbase + r;
        float val = acc[mi][ni][r] + bv;
        if (EP == 2) {
          out_fp32:
          outf[(size_t)m * 1024 + col] = val + resid[(size_t)m * 1024 + col];
        } else {
          const int bb = m >> 10, ss = m & 1023;
          const size_t o = ((size_t)(bb * NH_ + hidx) * S_ + ss) * D_ + d;
          if (EP == 0) {
            ush hh, ll;
            split2(val, hh, ll);
            oh[o] = hh;
            ol[o] = ll;
          } else {
            oh[o] = bf16_rne(val);
          }
        }
      }
    }
  }
}

// ---------------------------------------------------------------------------
// V transpose: vbf [bh][s][d] bf16 -> vT [bh][d][s] bf16. Grid (16, 64).
// ---------------------------------------------------------------------------
__global__ __launch_bounds__(256) void transpose_v(
    const ush* __restrict__ vbf, ush* __restrict__ vT) {
  __shared__ __align__(16) ush Ls[64][72];
  const int tid = threadIdx.x;
  const int s0 = blockIdx.x * 64, bh = blockIdx.y;
#pragma unroll
  for (int it = 0; it < 2; it++) {
    int flat = tid + 256 * it;
    int row = flat >> 3, dc = (flat & 7) * 8;
    *(uint4*)&Ls[row][dc] =
        *(const uint4*)&vbf[((size_t)bh * S_ + s0 + row) * D_ + dc];
  }
  __syncthreads();
#pragma unroll
  for (int it = 0; it < 2; it++) {
    int flat = tid + 256 * it;
    int drow = flat >> 3, sc = (flat & 7) * 8;
    ush v8[8];
#pragma unroll
    for (int u = 0; u < 8; u++) v8[u] = Ls[sc + u][drow];
    uint4 p;
    p.x = v8[0] | ((unsigned)v8[1] << 16); p.y = v8[2] | ((unsigned)v8[3] << 16);
    p.z = v8[4] | ((unsigned)v8[5] << 16); p.w = v8[6] | ((unsigned)v8[7] << 16);
    *(uint4*)&vT[((size_t)bh * D_ + drow) * S_ + s0 + sc] = p;
  }
}

// ---------------------------------------------------------------------------
// MFMA flash attention, pre-split operands. Block = (bh, 64 q-rows), 4 waves;
// wave w owns q-rows [16w,16w+16). Staging = pure uint4->b128 copies into
// padded LDS (all access <=2-way bank-aliased = free). Q frags direct from
// global. ctx written pre-split bf16 hi/lo [m][1024] for the O-proj GEMM.
// LDS 4*[64][72]*2B = 36864 B.
// ---------------------------------------------------------------------------
__global__ __launch_bounds__(256) void attn2(
    const ush* __restrict__ qh, const ush* __restrict__ ql,
    const ush* __restrict__ kh, const ush* __restrict__ kl,
    const ush* __restrict__ vT,
    ush* __restrict__ ch, ush* __restrict__ cl) {
  __shared__ __align__(16) ush Kh[64][72], Kl[64][72];
  __shared__ __align__(16) ush VTs[64][72];   // [d][j]
  __shared__ __align__(16) ush Pst[64][72];   // [m][j]
  const int tid = threadIdx.x;
  const int lane = tid & 63, wave = tid >> 6;
  const int l15 = lane & 15, quad = lane >> 4;
  const int w16 = wave * 16;
  const int bh = blockIdx.y;
  const int b = bh >> 4, h = bh & 15;
  const int q0 = blockIdx.x * 64;

  // ---- Q fragments straight from global (A-layout: m=l15, k=quad*8+j) ----
  const size_t qrow = ((size_t)bh * S_ + q0 + w16 + l15) * D_;
  frag16 a_h[2], a_l[2];
  a_h[0] = *(const frag16*)&qh[qrow + quad * 8];
  a_h[1] = *(const frag16*)&qh[qrow + 32 + quad * 8];
  a_l[0] = *(const frag16*)&ql[qrow + quad * 8];
  a_l[1] = *(const frag16*)&ql[qrow + 32 + quad * 8];

  f32x4 o[4];
  float mrow[4], lrow[4];
#pragma unroll
  for (int i = 0; i < 4; i++) {
    o[i] = (f32x4){0.f, 0.f, 0.f, 0.f};
    mrow[i] = -1e30f; lrow[i] = 0.f;
  }

  const size_t kbase = (size_t)bh * S_ * D_;
  const size_t vbase = (size_t)bh * D_ * S_;
  for (int j0 = 0; j0 < S_; j0 += 64) {
    __syncthreads();   // prior tile's frag reads done
#pragma unroll
    for (int it = 0; it < 2; it++) {
      const int flat = tid + 256 * it;
      const int row = flat >> 3, dc = (flat & 7) * 8;
      const size_t gk = kbase + (size_t)(j0 + row) * D_ + dc;
      *(uint4*)&Kh[row][dc] = *(const uint4*)&kh[gk];
      *(uint4*)&Kl[row][dc] = *(const uint4*)&kl[gk];
      *(uint4*)&VTs[row][dc] =
          *(const uint4*)&vT[vbase + (size_t)row * S_ + j0 + dc];
    }
    __syncthreads();

    // ---- S = Q.K^T (3-term split) ----
    f32x4 c4[4];
#pragma unroll
    for (int nt = 0; nt < 4; nt++) c4[nt] = (f32x4){0.f, 0.f, 0.f, 0.f};
#pragma unroll
    for (int kk = 0; kk < 2; kk++) {
#pragma unroll
      for (int nt = 0; nt < 4; nt++) {
        frag16 bh_ = *(const frag16*)&Kh[nt * 16 + l15][kk * 32 + quad * 8];
        frag16 bl_ = *(const frag16*)&Kl[nt * 16 + l15][kk * 32 + quad * 8];
        c4[nt] = __builtin_amdgcn_mfma_f32_16x16x32_bf16(a_h[kk], bh_, c4[nt], 0, 0, 0);
        c4[nt] = __builtin_amdgcn_mfma_f32_16x16x32_bf16(a_l[kk], bh_, c4[nt], 0, 0, 0);
        c4[nt] = __builtin_amdgcn_mfma_f32_16x16x32_bf16(a_h[kk], bl_, c4[nt], 0, 0, 0);
      }
    }

    // ---- bias + online softmax + P store (C-layout: row=quad*4+r, col=l15) --
    const bool far = (j0 >= q0 + 68) || (q0 >= j0 + 68);
#pragma unroll
    for (int r = 0; r < 4; r++) {
      const int qi = q0 + w16 + quad * 4 + r;
      float sv[4];
#pragma unroll
      for (int nt = 0; nt < 4; nt++) {
        const int jj = j0 + nt * 16 + l15;
        const float dist = fabsf((float)(qi - jj));
        const float pb = far ? 0.60653066f : __expf(-0.1f * fminf(dist, 5.0f));
        sv[nt] = (c4[nt][r] + pb) * 0.125f - 0.1f * dist;
      }
      float tm = fmaxf(fmaxf(sv[0], sv[1]), fmaxf(sv[2], sv[3]));
#pragma unroll
      for (int off = 1; off < 16; off <<= 1) tm = fmaxf(tm, __shfl_xor(tm, off));
      const float mnew = fmaxf(mrow[r], tm);
      const float alpha = __expf(mrow[r] - mnew);
      float rs = 0.f;
#pragma unroll
      for (int nt = 0; nt < 4; nt++) {
        sv[nt] = __expf(sv[nt] - mnew);
        rs += sv[nt];
      }
#pragma unroll
      for (int off = 1; off < 16; off <<= 1) rs += __shfl_xor(rs, off);
      lrow[r] = lrow[r] * alpha + rs;
      mrow[r] = mnew;
#pragma unroll
      for (int dt = 0; dt < 4; dt++) o[dt][r] *= alpha;
#pragma unroll
      for (int nt = 0; nt < 4; nt++)
        Pst[w16 + quad * 4 + r][nt * 16 + l15] = bf16_rne(sv[nt]);
    }

    // ---- PV (own rows only; same-wave LDS ordering) ----
    frag16 pa[2];
#pragma unroll
    for (int kk = 0; kk < 2; kk++)
      pa[kk] = *(const frag16*)&Pst[w16 + l15][kk * 32 + quad * 8];
#pragma unroll
    for (int dt = 0; dt < 4; dt++) {
      frag16 vb0 = *(const frag16*)&VTs[dt * 16 + l15][quad * 8];
      frag16 vb1 = *(const frag16*)&VTs[dt * 16 + l15][32 + quad * 8];
      o[dt] = __builtin_amdgcn_mfma_f32_16x16x32_bf16(pa[0], vb0, o[dt], 0, 0, 0);
      o[dt] = __builtin_amdgcn_mfma_f32_16x16x32_bf16(pa[1], vb1, o[dt], 0, 0, 0);
    }
  }

  // ---- normalize + write ctx pre-split bf16 [m][1024] ----
#pragma unroll
  for (int r = 0; r < 4; r++) {
    const float inv = 1.0f / lrow[r];
    const size_t rowp =
        ((size_t)(b * S_ + q0 + w16 + quad * 4 + r)) * H_ + h * 64;
#pragma unroll
    for (int dt = 0; dt < 4; dt++) {
      ush hh, ll;
      split2(o[dt][r] * inv, hh, ll);
      ch[rowp + dt * 16 + l15] = hh;
      cl[rowp + dt * 16 + l15] = ll;
    }
  }
}

// ---------------------------------------------------------------------------
// Fused LayerNorm + span logits: one block per row.
// logits[row][9] = LN(y[row]) @ Ws + bs
// ---------------------------------------------------------------------------
__global__ __launch_bounds__(256) void ln_span(
    const float* __restrict__ y, const float* __restrict__ g,
    const float* __restrict__ bta, const float* __restrict__ Wsp,
    const float* __restrict__ bs, float* __restrict__ logits) {
  const int row = blockIdx.x;
  const int tid = threadIdx.x, lane = tid & 63, wave = tid >> 6;
  const float* yr = y + (size_t)row * 1024;
  float vals[4], s = 0.f, s2 = 0.f;
#pragma unroll
  for (int i = 0; i < 4; i++) {
    float t = yr[tid + i * 256];
    vals[i] = t; s += t; s2 += t * t;
  }
#pragma unroll
  for (int off = 32; off; off >>= 1) {
    s += __shfl_xor(s, off);
    s2 += __shfl_xor(s2, off);
  }
  __shared__ float red[8];
  __shared__ float red9[4][12];
  if (lane == 0) { red[wave] = s; red[4 + wave] = s2; }
  __syncthreads();
  s = red[0] + red[1] + red[2] + red[3];
  s2 = red[4] + red[5] + red[6] + red[7];
  const float mu = s * (1.0f / 1024.0f);
  const float var = s2 * (1.0f / 1024.0f) - mu * mu;
  const float inv = rsqrtf(var + 1e-5f);

  float lg[9];
#pragma unroll
  for (int l = 0; l < 9; l++) lg[l] = 0.f;
#pragma unroll
  for (int i = 0; i < 4; i++) {
    const int hh = tid + i * 256;
    const float yn = (vals[i] - mu) * inv * g[hh] + bta[hh];
#pragma unroll
    for (int l = 0; l < 9; l++) lg[l] += yn * Wsp[hh * 9 + l];
  }
#pragma unroll
  for (int l = 0; l < 9; l++) {
#pragma unroll
    for (int off = 32; off; off >>= 1) lg[l] += __shfl_xor(lg[l], off);
  }
  if (lane == 0) {
#pragma unroll
    for (int l = 0; l < 9; l++) red9[wave][l] = lg[l];
  }
  __syncthreads();
  if (tid < 9) {
    logits[(size_t)row * 9 + tid] =
        red9[0][tid] + red9[1][tid] + red9[2][tid] + red9[3][tid] + bs[tid];
  }
}

// ---------------------------------------------------------------------------
// Entity-bias adjustment + FP32 output. One thread per token.
// ---------------------------------------------------------------------------
__global__ __launch_bounds__(256) void final_kernel(
    const float* __restrict__ logits, const float* __restrict__ eb,
    float* __restrict__ out) {
  const int m = blockIdx.x * 256 + threadIdx.x;
  const int i = m & 1023;
  float cur[9];
#pragma unroll
  for (int l = 0; l < 9; l++) cur[l] = logits[(size_t)m * 9 + l];
  if (i > 0) {
    const float* prev = logits + (size_t)(m - 1) * 9;
    int am = 0;
    float best = prev[0];
#pragma unroll
    for (int l = 1; l < 9; l++) {
      float pv = prev[l];
      if (pv > best) { best = pv; am = l; }  // strict > == first-max argmax
    }
    if (am == 1) cur[2] += 2.0f * eb[2];
  }
#pragma unroll
  for (int l = 0; l < 9; l++) out[(size_t)m * 9 + l] = cur[l];
}

// ---------------------------------------------------------------------------
extern "C" void kernel_launch(void* const* d_in, const int* in_sizes, int n_in,
                              void* d_out, int out_size, void* d_ws, size_t ws_size,
                              hipStream_t stream) {
  const float* x    = (const float*)d_in[0];
  const float* Wq   = (const float*)d_in[1];
  const float* bq   = (const float*)d_in[2];
  const float* Wk   = (const float*)d_in[3];
  const float* bk   = (const float*)d_in[4];
  const float* Wv   = (const float*)d_in[5];
  const float* bv   = (const float*)d_in[6];
  const float* Wo   = (const float*)d_in[7];
  const float* bo   = (const float*)d_in[8];
  const float* ln_g = (const float*)d_in[9];
  const float* ln_b = (const float*)d_in[10];
  const float* Ws   = (const float*)d_in[11];
  const float* bs   = (const float*)d_in[12];
  const float* eb   = (const float*)d_in[13];
  float* out = (float*)d_out;       // output fp32 (verified R5)
  char* W8 = (char*)d_ws;

  // ---- ws layout (64 MB envelope, proven >= 64 MB since R5) ----
  ush* WoT_h = (ush*)(W8 + 0 * MB_);
  ush* WoT_l = (ush*)(W8 + 2 * MB_);
  ush* WqT_h = (ush*)(W8 + 4 * MB_);
  ush* WqT_l = (ush*)(W8 + 6 * MB_);
  ush* WkT_h = (ush*)(W8 + 8 * MB_);
  ush* WkT_l = (ush*)(W8 + 10 * MB_);
  ush* WvT_h = (ush*)(W8 + 12 * MB_);
  ush* WvT_l = (ush*)(W8 + 14 * MB_);
  ush* qh    = (ush*)(W8 + 16 * MB_);
  ush* ql    = (ush*)(W8 + 24 * MB_);
  ush* kh    = (ush*)(W8 + 32 * MB_);
  ush* kl    = (ush*)(W8 + 40 * MB_);
  ush* vbf   = (ush*)(W8 + 48 * MB_);
  ush* vT    = (ush*)(W8 + 56 * MB_);
  // aliases (dead-slot reuse, ordering on one stream):
  ush*   ctxh   = (ush*)(W8 + 4 * MB_);    // over WqT/WkT_h (dead after QKV)
  ush*   ctxl   = (ush*)(W8 + 48 * MB_);   // over vbf (dead after transpose)
  float* y_ws   = (float*)(W8 + 32 * MB_); // over kh/kl (dead after attn)
  float* lg_ws  = (float*)(W8 + 56 * MB_); // over vT (dead after attn)

  split_wT4<<<dim3(16, 16, 4), 256, 0, stream>>>(
      Wq, Wk, Wv, Wo, WqT_h, WqT_l, WkT_h, WkT_l, WvT_h, WvT_l, WoT_h, WoT_l);

  dim3 g64(16, 64);
  gemm_bf<0, 0><<<g64, 256, 0, stream>>>(x, nullptr, nullptr, WqT_h, WqT_l,
                                         bq, nullptr, nullptr, qh, ql);
  gemm_bf<0, 0><<<g64, 256, 0, stream>>>(x, nullptr, nullptr, WkT_h, WkT_l,
                                         bk, nullptr, nullptr, kh, kl);
  gemm_bf<0, 1><<<g64, 256, 0, stream>>>(x, nullptr, nullptr, WvT_h, WvT_l,
                                         bv, nullptr, nullptr, vbf, nullptr);
  transpose_v<<<dim3(16, 64), 256, 0, stream>>>(vbf, vT);
  attn2<<<dim3(16, 64), 256, 0, stream>>>(qh, ql, kh, kl, vT, ctxh, ctxl);
  gemm_bf<1, 2><<<g64, 256, 0, stream>>>(nullptr, ctxh, ctxl, WoT_h, WoT_l,
                                         bo, x, y_ws, nullptr, nullptr);
  ln_span<<<4096, 256, 0, stream>>>(y_ws, ln_g, ln_b, Ws, bs, lg_ws);
  final_kernel<<<16, 256, 0, stream>>>(lg_ws, eb, out);
}